// Round 5
// baseline (697.986 us; speedup 1.0000x reference)
//
#include <hip/hip_runtime.h>
#include <hip/hip_cooperative_groups.h>

namespace cg = cooperative_groups;

// QuantumSpectralConv: x[4,128,128,64] f32, W[16,16,64,64,4] re/im planes.
//   x_ft = DFT_{H,W}(x) truncated to 16x16 modes
//   om[b,k,m,o] = sum_{n,c} x_ft[b,k,n,c] * (sum_s W[m,n,c,o,s]) / 2
//   out = Re(iDFT zero-padded)  -> [4,128,128,64] f32
//
// Primary path: ONE cooperative kernel, 512 blocks x 256 thr (2 blk/CU
// co-resident), 5 stages separated by grid.sync() + agent fences
// (cross-XCD L2 wb/inv -- poison fill leaves stale lines in other L2s).
// Fallback path (if cooperative launch fails/capture-unsupported): the
// round-3 six-kernel pipeline, unchanged.

static constexpr int BATCH = 4;

// ---- fused-path ws offsets (floats) ----
static constexpr size_t F_TMP = 0;              // tmp1: 524288 complex (4.2MB)
static constexpr size_t F_XFT = 1048576;        // 65536 complex
static constexpr size_t F_P   = 1179648;        // 524288 complex (4.2MB)
static constexpr size_t F_U   = 2228224;        // 524288 complex (4.2MB)

// ---- fallback-path ws offsets (floats) ----
static constexpr size_t XFT_OFF = 0;
static constexpr size_t OM_OFF  = 131072;
static constexpr size_t BIG_OFF = 262144;

__device__ __forceinline__ void init_trig_lds(float2* twl) {
    if (threadIdx.x < 128) {
        float s, c;
        sincosf(6.283185307179586f * (float)threadIdx.x * 0.0078125f, &s, &c);
        twl[threadIdx.x] = make_float2(c, s);
    }
}

// ============================ FUSED KERNEL ============================
__global__ __launch_bounds__(256, 2) void k_fused(const float* __restrict__ x,
                                                  const float* __restrict__ wr,
                                                  const float* __restrict__ wi,
                                                  float* __restrict__ out,
                                                  float* __restrict__ ws) {
    __shared__ __align__(16) char smem[43008];    // union across stages
    __shared__ float2 twl[128];
    cg::grid_group grid = cg::this_grid();

    float2* tmp1 = (float2*)(ws + F_TMP);
    float2* xft  = (float2*)(ws + F_XFT);
    float2* P    = (float2*)(ws + F_P);
    float2* u    = (float2*)(ws + F_U);

    const int bid = blockIdx.x;                   // 512 blocks
    const int tid = threadIdx.x;                  // 256 threads
    init_trig_lds(twl);

    // ---------- Stage A: DFT over W ----------
    // block = (b,h); tmp1[b,h,n,c] = sum_w x[b,h,w,c] e^{-2pi i n w/128}
    {
        float4* xs = (float4*)smem;               // [128 w][16 c4] 32KB
        const float4* x4 = reinterpret_cast<const float4*>(x) + (size_t)bid * 2048;
        #pragma unroll
        for (int i = 0; i < 8; ++i) xs[tid + 256 * i] = x4[tid + 256 * i];
        __syncthreads();
        const int n  = tid >> 4;
        const int c4 = tid & 15;
        float4 ar = make_float4(0.f, 0.f, 0.f, 0.f);
        float4 ai = make_float4(0.f, 0.f, 0.f, 0.f);
        int t = 0;                                // (n*w) & 127
        #pragma unroll 8
        for (int w = 0; w < 128; ++w) {
            const float4 v  = xs[w * 16 + c4];
            const float2 tw = twl[t];
            t = (t + n) & 127;
            ar.x += v.x * tw.x; ai.x -= v.x * tw.y;
            ar.y += v.y * tw.x; ai.y -= v.y * tw.y;
            ar.z += v.z * tw.x; ai.z -= v.z * tw.y;
            ar.w += v.w * tw.x; ai.w -= v.w * tw.y;
        }
        float4* o = reinterpret_cast<float4*>(tmp1 + ((size_t)bid * 16 + n) * 64 + c4 * 4);
        o[0] = make_float4(ar.x, ai.x, ar.y, ai.y);
        o[1] = make_float4(ar.z, ai.z, ar.w, ai.w);
    }
    __threadfence(); grid.sync(); __threadfence();

    // ---------- Stage B: DFT over H ----------
    // block = (b,k,nh); xft[(b*16+k)*1024+n*64+c] = sum_h tmp1[b,h,n,c] e^{-2pi i k h/128}
    {
        const int nh = bid & 7;
        const int k  = (bid >> 3) & 15;
        const int b  = bid >> 7;
        const int c  = tid & 63;
        const int n1 = (tid >> 6) & 1;
        const int hq = tid >> 7;                  // 0/1: 64-h halves
        const int n  = nh * 2 + n1;
        const float2* src = tmp1 + (size_t)b * 131072 + n * 64 + c;
        float2 acc = make_float2(0.f, 0.f);
        const int h0 = hq * 64;
        int t = (k * h0) & 127;
        #pragma unroll 8
        for (int j = 0; j < 64; ++j) {
            const float2 a  = src[(size_t)(h0 + j) * 1024];
            const float2 tw = twl[t];
            t = (t + k) & 127;
            acc.x += a.x * tw.x + a.y * tw.y;
            acc.y += a.y * tw.x - a.x * tw.y;
        }
        float2* red = (float2*)smem;              // 128 float2
        if (hq) red[n1 * 64 + c] = acc;
        __syncthreads();
        if (!hq) {
            const float2 r = red[n1 * 64 + c];
            acc.x += r.x; acc.y += r.y;
            xft[(size_t)(b * 16 + k) * 1024 + n * 64 + c] = acc;
        }
    }
    __threadfence(); grid.sync(); __threadfence();

    // ---------- Stage C: complex GEMM, split-K by n-octet ----------
    // block = (m,oq,noct): out tile [64 rows][16 oo], K=128 via 2 slabs of 64.
    {
        float2* As = (float2*)smem;               // [64 kk][66 row] 33792B
        float2* Bs = (float2*)(smem + 33792);     // [64 kk][18 oo]   9216B
        const int noct = bid & 7;
        const int oq   = (bid >> 3) & 3;
        const int m    = bid >> 5;
        const int ci = tid & 7;                   // oo pair 2ci,2ci+1
        const int ri = tid >> 3;                  // rows 2ri,2ri+1
        float accr[2][2] = {}, acci[2][2] = {};
        for (int nn = 0; nn < 2; ++nn) {
            const int n = noct * 2 + nn;
            #pragma unroll
            for (int i = 0; i < 8; ++i) {         // stage A-slab (2048)
                const int idx = tid + 256 * i;
                const int row = idx >> 5, k2 = idx & 31;
                const float4 q = *reinterpret_cast<const float4*>(
                    &xft[(size_t)row * 1024 + n * 64 + 2 * k2]);
                As[(2 * k2) * 66 + row]     = make_float2(q.x, q.y);
                As[(2 * k2 + 1) * 66 + row] = make_float2(q.z, q.w);
            }
            #pragma unroll
            for (int i = 0; i < 4; ++i) {         // stage B-slab (1024), sum s
                const int idx = tid + 256 * i;
                const int cc = idx >> 4, oo = idx & 15;
                const size_t wb = ((size_t)((m * 16 + n) * 64 + cc) * 64 + oq * 16 + oo) * 4;
                const float4 r4 = *reinterpret_cast<const float4*>(wr + wb);
                const float4 i4 = *reinterpret_cast<const float4*>(wi + wb);
                Bs[cc * 18 + oo] = make_float2((r4.x + r4.y + r4.z + r4.w) * 0.5f,
                                               (i4.x + i4.y + i4.z + i4.w) * 0.5f);
            }
            __syncthreads();
            #pragma unroll 8
            for (int kk = 0; kk < 64; ++kk) {
                const float4 a01 = *reinterpret_cast<const float4*>(&As[kk * 66 + 2 * ri]);
                const float4 bb  = *reinterpret_cast<const float4*>(&Bs[kk * 18 + 2 * ci]);
                accr[0][0] += a01.x * bb.x - a01.y * bb.y;
                acci[0][0] += a01.x * bb.y + a01.y * bb.x;
                accr[0][1] += a01.x * bb.z - a01.y * bb.w;
                acci[0][1] += a01.x * bb.w + a01.y * bb.z;
                accr[1][0] += a01.z * bb.x - a01.w * bb.y;
                acci[1][0] += a01.z * bb.y + a01.w * bb.x;
                accr[1][1] += a01.z * bb.z - a01.w * bb.w;
                acci[1][1] += a01.z * bb.w + a01.w * bb.z;
            }
            __syncthreads();
        }
        float2* Pb = P + (size_t)bid * 1024;      // [row 64][oo 16]
        #pragma unroll
        for (int r = 0; r < 2; ++r) {
            const int row = 2 * ri + r;
            *reinterpret_cast<float4*>(&Pb[row * 16 + 2 * ci]) =
                make_float4(accr[r][0], acci[r][0], accr[r][1], acci[r][1]);
        }
    }
    __threadfence(); grid.sync(); __threadfence();

    // ---------- Stage D: reduce partials + inverse DFT over H ----------
    // block = (b,m,hc): om_s[k][o] = sum_noct P[...]; u[b,h,m,o] = sum_k om e^{+2pi i k h/128}
    {
        float2* om_s = (float2*)smem;             // [16 k][64 o] 8KB
        const int hc = bid & 7;                   // 16-h chunk
        const int m  = (bid >> 3) & 15;
        const int b  = bid >> 7;
        #pragma unroll
        for (int j = 0; j < 4; ++j) {
            const int e = tid + 256 * j;          // 1024 = k*64+o
            const int k = e >> 6, o = e & 63;
            const int oq = o >> 4, oo = o & 15;
            const float2* p = P + (size_t)(m * 32 + oq * 8) * 1024 + (b * 16 + k) * 16 + oo;
            float2 acc = make_float2(0.f, 0.f);
            #pragma unroll
            for (int noct = 0; noct < 8; ++noct) {
                const float2 v = p[(size_t)noct * 1024];
                acc.x += v.x; acc.y += v.y;
            }
            om_s[e] = acc;
        }
        __syncthreads();
        const int o  = tid & 63;
        const int hq = tid >> 6;                  // 4-h sub-chunks
        float2 v[16];
        #pragma unroll
        for (int k = 0; k < 16; ++k) v[k] = om_s[k * 64 + o];
        #pragma unroll
        for (int i = 0; i < 4; ++i) {
            const int h = hc * 16 + hq * 4 + i;
            float re = 0.f, im = 0.f;
            int t = 0;                            // (k*h) & 127
            #pragma unroll
            for (int k = 0; k < 16; ++k) {
                const float2 tw = twl[t];
                t = (t + h) & 127;
                re += v[k].x * tw.x - v[k].y * tw.y;
                im += v[k].x * tw.y + v[k].y * tw.x;
            }
            u[((size_t)(b * 128 + h) * 16 + m) * 64 + o] = make_float2(re, im);
        }
    }
    __threadfence(); grid.sync(); __threadfence();

    // ---------- Stage E: inverse DFT over W + real + 1/16384 ----------
    // block = (b,h)
    {
        const int o4 = tid & 15;                  // 4 o's
        const int wg = tid >> 4;                  // 8 w's
        const float2* ub = u + (size_t)bid * 1024 + o4 * 4;
        float2 v[16][4];
        #pragma unroll
        for (int mm = 0; mm < 16; ++mm) {
            const float4 q0 = *reinterpret_cast<const float4*>(ub + (size_t)mm * 64);
            const float4 q1 = *reinterpret_cast<const float4*>(ub + (size_t)mm * 64 + 2);
            v[mm][0] = make_float2(q0.x, q0.y);
            v[mm][1] = make_float2(q0.z, q0.w);
            v[mm][2] = make_float2(q1.x, q1.y);
            v[mm][3] = make_float2(q1.z, q1.w);
        }
        const float inv = 1.0f / 16384.0f;
        #pragma unroll
        for (int i = 0; i < 8; ++i) {
            const int w = wg * 8 + i;
            float4 acc = make_float4(0.f, 0.f, 0.f, 0.f);
            int t = 0;                            // (m*w) & 127
            #pragma unroll
            for (int mm = 0; mm < 16; ++mm) {
                const float2 tw = twl[t];
                t = (t + w) & 127;
                acc.x += v[mm][0].x * tw.x - v[mm][0].y * tw.y;
                acc.y += v[mm][1].x * tw.x - v[mm][1].y * tw.y;
                acc.z += v[mm][2].x * tw.x - v[mm][2].y * tw.y;
                acc.w += v[mm][3].x * tw.x - v[mm][3].y * tw.y;
            }
            acc.x *= inv; acc.y *= inv; acc.z *= inv; acc.w *= inv;
            *reinterpret_cast<float4*>(out + ((size_t)bid * 128 + w) * 64 + o4 * 4) = acc;
        }
    }
}

// ======================= FALLBACK (round-3) PATH =======================
__global__ __launch_bounds__(256) void k_dft_w(const float* __restrict__ x,
                                               float2* __restrict__ tmp1) {
    __shared__ float4 xs[2048];
    __shared__ float2 twl[128];
    init_trig_lds(twl);
    const int bid = blockIdx.x;
    const float4* x4 = reinterpret_cast<const float4*>(x) + (size_t)bid * 2048;
    #pragma unroll
    for (int i = 0; i < 8; ++i) xs[threadIdx.x + 256 * i] = x4[threadIdx.x + 256 * i];
    __syncthreads();
    const int n  = threadIdx.x >> 4;
    const int c4 = threadIdx.x & 15;
    float4 ar = make_float4(0.f, 0.f, 0.f, 0.f);
    float4 ai = make_float4(0.f, 0.f, 0.f, 0.f);
    int t = 0;
    #pragma unroll 8
    for (int w = 0; w < 128; ++w) {
        const float4 v  = xs[w * 16 + c4];
        const float2 tw = twl[t];
        t = (t + n) & 127;
        ar.x += v.x * tw.x; ai.x -= v.x * tw.y;
        ar.y += v.y * tw.x; ai.y -= v.y * tw.y;
        ar.z += v.z * tw.x; ai.z -= v.z * tw.y;
        ar.w += v.w * tw.x; ai.w -= v.w * tw.y;
    }
    float4* o = reinterpret_cast<float4*>(tmp1 + ((size_t)bid * 16 + n) * 64 + c4 * 4);
    o[0] = make_float4(ar.x, ai.x, ar.y, ai.y);
    o[1] = make_float4(ar.z, ai.z, ar.w, ai.w);
}

__global__ __launch_bounds__(256) void k_dft_h(const float2* __restrict__ tmp1,
                                               float2* __restrict__ xft) {
    __shared__ float2 twl[128];
    init_trig_lds(twl);
    __syncthreads();
    const int tid = blockIdx.x * 256 + threadIdx.x;
    const int c = tid & 63;
    const int n = (tid >> 6) & 15;
    const int k = (tid >> 10) & 15;
    const int b = tid >> 14;
    const float2* src = tmp1 + (size_t)b * 131072 + n * 64 + c;
    float2 acc = make_float2(0.f, 0.f);
    int t = 0;
    #pragma unroll 8
    for (int h = 0; h < 128; ++h) {
        const float2 a  = src[(size_t)h * 1024];
        const float2 tw = twl[t];
        t = (t + k) & 127;
        acc.x += a.x * tw.x + a.y * tw.y;
        acc.y += a.y * tw.x - a.x * tw.y;
    }
    xft[(size_t)(b * 16 + k) * 1024 + n * 64 + c] = acc;
}

__global__ __launch_bounds__(256) void k_gemm(const float2* __restrict__ xft,
                                              const float* __restrict__ wr,
                                              const float* __restrict__ wi,
                                              float2* __restrict__ P) {
    __shared__ float2 As[64 * 66];
    __shared__ float2 Bs[64 * 34];
    const int bid  = blockIdx.x;
    const int noct = bid & 7;
    const int oh   = (bid >> 3) & 1;
    const int m    = bid >> 4;
    const int ci = threadIdx.x & 15;
    const int ri = threadIdx.x >> 4;
    float accr[4][2] = {}, acci[4][2] = {};
    for (int nn = 0; nn < 2; ++nn) {
        const int n = noct * 2 + nn;
        #pragma unroll
        for (int i = 0; i < 8; ++i) {
            const int idx = threadIdx.x + 256 * i;
            const int row = idx >> 5, k2 = idx & 31;
            const float4 q = *reinterpret_cast<const float4*>(
                &xft[(size_t)row * 1024 + n * 64 + 2 * k2]);
            As[(2 * k2) * 66 + row]     = make_float2(q.x, q.y);
            As[(2 * k2 + 1) * 66 + row] = make_float2(q.z, q.w);
        }
        #pragma unroll
        for (int i = 0; i < 8; ++i) {
            const int idx = threadIdx.x + 256 * i;
            const int cc = idx >> 5, oo = idx & 31;
            const size_t wb = ((size_t)((m * 16 + n) * 64 + cc) * 64 + oh * 32 + oo) * 4;
            const float4 r4 = *reinterpret_cast<const float4*>(wr + wb);
            const float4 i4 = *reinterpret_cast<const float4*>(wi + wb);
            Bs[cc * 34 + oo] = make_float2((r4.x + r4.y + r4.z + r4.w) * 0.5f,
                                           (i4.x + i4.y + i4.z + i4.w) * 0.5f);
        }
        __syncthreads();
        #pragma unroll 8
        for (int kk = 0; kk < 64; ++kk) {
            const float4 a01 = *reinterpret_cast<const float4*>(&As[kk * 66 + 4 * ri]);
            const float4 a23 = *reinterpret_cast<const float4*>(&As[kk * 66 + 4 * ri + 2]);
            const float4 bb  = *reinterpret_cast<const float4*>(&Bs[kk * 34 + 2 * ci]);
            const float arr[4] = {a01.x, a01.z, a23.x, a23.z};
            const float aii[4] = {a01.y, a01.w, a23.y, a23.w};
            #pragma unroll
            for (int r = 0; r < 4; ++r) {
                accr[r][0] += arr[r] * bb.x - aii[r] * bb.y;
                acci[r][0] += arr[r] * bb.y + aii[r] * bb.x;
                accr[r][1] += arr[r] * bb.z - aii[r] * bb.w;
                acci[r][1] += arr[r] * bb.w + aii[r] * bb.z;
            }
        }
        __syncthreads();
    }
    float2* Pb = P + (size_t)bid * 2048;
    #pragma unroll
    for (int r = 0; r < 4; ++r) {
        const int row = 4 * ri + r;
        *reinterpret_cast<float4*>(&Pb[row * 32 + 2 * ci]) =
            make_float4(accr[r][0], acci[r][0], accr[r][1], acci[r][1]);
    }
}

__global__ __launch_bounds__(256) void k_reduce(const float2* __restrict__ P,
                                                float2* __restrict__ om) {
    const int gtid = blockIdx.x * 256 + threadIdx.x;
    const int o   = gtid & 63;
    const int mm  = (gtid >> 6) & 15;
    const int row = gtid >> 10;
    const int oh = o >> 5, oo = o & 31;
    const float2* p = P + (size_t)((mm * 2 + oh) * 8) * 2048 + row * 32 + oo;
    float2 acc = make_float2(0.f, 0.f);
    #pragma unroll
    for (int nq = 0; nq < 8; ++nq) {
        const float2 v = p[(size_t)nq * 2048];
        acc.x += v.x; acc.y += v.y;
    }
    om[(size_t)row * 1024 + mm * 64 + o] = acc;
}

__global__ __launch_bounds__(256) void k_ifft_h(const float2* __restrict__ om,
                                                float2* __restrict__ u) {
    __shared__ float2 twl[128];
    init_trig_lds(twl);
    const int bid = blockIdx.x;
    const int hq = bid & 3;
    const int m  = (bid >> 2) & 15;
    const int b  = bid >> 6;
    const int o  = threadIdx.x & 63;
    const int hs = threadIdx.x >> 6;
    __syncthreads();
    float2 v[16];
    #pragma unroll
    for (int k = 0; k < 16; ++k)
        v[k] = om[(size_t)(b * 16 + k) * 1024 + m * 64 + o];
    #pragma unroll
    for (int i = 0; i < 8; ++i) {
        const int h = hq * 32 + hs * 8 + i;
        float re = 0.f, im = 0.f;
        int t = 0;
        #pragma unroll
        for (int k = 0; k < 16; ++k) {
            const float2 tw = twl[t];
            t = (t + h) & 127;
            re += v[k].x * tw.x - v[k].y * tw.y;
            im += v[k].x * tw.y + v[k].y * tw.x;
        }
        u[((size_t)(b * 128 + h) * 16 + m) * 64 + o] = make_float2(re, im);
    }
}

__global__ __launch_bounds__(256) void k_ifft_w(const float2* __restrict__ u,
                                                float* __restrict__ out) {
    __shared__ float2 twl[128];
    init_trig_lds(twl);
    const int bid = blockIdx.x;
    const int o4 = threadIdx.x & 15;
    const int wg = threadIdx.x >> 4;
    __syncthreads();
    const float2* ub = u + (size_t)bid * 1024 + o4 * 4;
    float2 v[16][4];
    #pragma unroll
    for (int mm = 0; mm < 16; ++mm) {
        const float4 q0 = *reinterpret_cast<const float4*>(ub + (size_t)mm * 64);
        const float4 q1 = *reinterpret_cast<const float4*>(ub + (size_t)mm * 64 + 2);
        v[mm][0] = make_float2(q0.x, q0.y);
        v[mm][1] = make_float2(q0.z, q0.w);
        v[mm][2] = make_float2(q1.x, q1.y);
        v[mm][3] = make_float2(q1.z, q1.w);
    }
    const float inv = 1.0f / 16384.0f;
    #pragma unroll
    for (int i = 0; i < 8; ++i) {
        const int w = wg * 8 + i;
        float4 acc = make_float4(0.f, 0.f, 0.f, 0.f);
        int t = 0;
        #pragma unroll
        for (int mm = 0; mm < 16; ++mm) {
            const float2 tw = twl[t];
            t = (t + w) & 127;
            acc.x += v[mm][0].x * tw.x - v[mm][0].y * tw.y;
            acc.y += v[mm][1].x * tw.x - v[mm][1].y * tw.y;
            acc.z += v[mm][2].x * tw.x - v[mm][2].y * tw.y;
            acc.w += v[mm][3].x * tw.x - v[mm][3].y * tw.y;
        }
        acc.x *= inv; acc.y *= inv; acc.z *= inv; acc.w *= inv;
        *reinterpret_cast<float4*>(out + ((size_t)bid * 128 + w) * 64 + o4 * 4) = acc;
    }
}

extern "C" void kernel_launch(void* const* d_in, const int* in_sizes, int n_in,
                              void* d_out, int out_size, void* d_ws, size_t ws_size,
                              hipStream_t stream) {
    const float* x  = (const float*)d_in[0];
    const float* wr = (const float*)d_in[1];
    const float* wi = (const float*)d_in[2];
    float* outp = (float*)d_out;
    float* wsf  = (float*)d_ws;

    // primary: single cooperative kernel
    void* args[] = {(void*)&x, (void*)&wr, (void*)&wi, (void*)&outp, (void*)&wsf};
    hipError_t err = hipLaunchCooperativeKernel((const void*)k_fused, dim3(512),
                                                dim3(256), args, 0, stream);
    if (err == hipSuccess) return;

    // fallback: round-3 six-kernel pipeline
    float2* xft = (float2*)(wsf + XFT_OFF);
    float2* om  = (float2*)(wsf + OM_OFF);
    float2* big = (float2*)(wsf + BIG_OFF);
    k_dft_w <<<BATCH * 128, 256, 0, stream>>>(x, big);
    k_dft_h <<<256, 256, 0, stream>>>(big, xft);
    k_gemm  <<<256, 256, 0, stream>>>(xft, wr, wi, big);
    k_reduce<<<256, 256, 0, stream>>>(big, om);
    k_ifft_h<<<256, 256, 0, stream>>>(om, big);
    k_ifft_w<<<BATCH * 128, 256, 0, stream>>>(big, outp);
}

// Round 6
// 168.285 us; speedup vs baseline: 4.1476x; 4.1476x over previous
//
#include <hip/hip_runtime.h>

// QuantumSpectralConv: x[4,128,128,64] f32, W[16,16,64,64,4] re/im planes.
//   x_ft = DFT_{H,W}(x) truncated to 16x16 modes
//   om[b,k,m,o] = sum_{n,c} x_ft[b,k,n,c] * (sum_s W[m,n,c,o,s]) / 2
//   out = Re(iDFT zero-padded)  -> [4,128,128,64] f32
//
// 4-kernel pipeline (no atomics, no memset, NO grid.sync -- R5 showed
// cooperative grid barriers cost ~100us each on 8 XCDs):
//   dft_w -> dft_h -> gemm2 (full-K, writes omT k-innermost) -> idft (fused
//   inverse H+W; om is 0.5MB L2-hot so each (b,h) block rebuilds its u-row).

static constexpr int BATCH = 4;

// float offsets into workspace (5.24 MB total)
static constexpr size_t TMP_OFF = 0;          // tmp1: 524288 complex (4.2MB)
static constexpr size_t XFT_OFF = 1048576;    // 65536 complex (0.5MB)
static constexpr size_t OMT_OFF = 1179648;    // 65536 complex (0.5MB)

// twl[t] = (cos, sin)(2*pi*t/128), built by threads 0..127
__device__ __forceinline__ void init_trig_lds(float2* twl) {
    if (threadIdx.x < 128) {
        float s, c;
        sincosf(6.283185307179586f * (float)threadIdx.x * 0.0078125f, &s, &c);
        twl[threadIdx.x] = make_float2(c, s);
    }
}

// DFT over W: tmp1[b,h,n,c] = sum_w x[b,h,w,c] * e^{-2pi i n w/128}, n<16
// block per (b,h) = 512 blocks. Thread: one n (tid>>4), 4 c's (tid&15).
__global__ __launch_bounds__(256) void k_dft_w(const float* __restrict__ x,
                                               float2* __restrict__ tmp1) {
    __shared__ float4 xs[2048];                       // [128 w][16 c4] = 32KB
    __shared__ float2 twl[128];
    init_trig_lds(twl);
    const int bid = blockIdx.x;                       // b*128 + h
    const float4* x4 = reinterpret_cast<const float4*>(x) + (size_t)bid * 2048;
    #pragma unroll
    for (int i = 0; i < 8; ++i) xs[threadIdx.x + 256 * i] = x4[threadIdx.x + 256 * i];
    __syncthreads();
    const int n  = threadIdx.x >> 4;
    const int c4 = threadIdx.x & 15;
    float4 ar = make_float4(0.f, 0.f, 0.f, 0.f);
    float4 ai = make_float4(0.f, 0.f, 0.f, 0.f);
    int t = 0;                                        // t = (n*w) & 127
    #pragma unroll 8
    for (int w = 0; w < 128; ++w) {
        const float4 v  = xs[w * 16 + c4];
        const float2 tw = twl[t];
        t = (t + n) & 127;
        ar.x += v.x * tw.x; ai.x -= v.x * tw.y;
        ar.y += v.y * tw.x; ai.y -= v.y * tw.y;
        ar.z += v.z * tw.x; ai.z -= v.z * tw.y;
        ar.w += v.w * tw.x; ai.w -= v.w * tw.y;
    }
    float4* o = reinterpret_cast<float4*>(tmp1 + ((size_t)bid * 16 + n) * 64 + c4 * 4);
    o[0] = make_float4(ar.x, ai.x, ar.y, ai.y);
    o[1] = make_float4(ar.z, ai.z, ar.w, ai.w);
}

// DFT over H: xft[(b*16+k)*1024 + n*64+c] = sum_h tmp1[b,h,n,c] * e^{-2pi i k h/128}
// one thread per output; k,b block-uniform -> twiddle LDS loads broadcast.
__global__ __launch_bounds__(256) void k_dft_h(const float2* __restrict__ tmp1,
                                               float2* __restrict__ xft) {
    __shared__ float2 twl[128];
    init_trig_lds(twl);
    __syncthreads();
    const int tid = blockIdx.x * 256 + threadIdx.x;
    const int c = tid & 63;
    const int n = (tid >> 6) & 15;
    const int k = (tid >> 10) & 15;
    const int b = tid >> 14;
    const float2* src = tmp1 + (size_t)b * 131072 + n * 64 + c;  // + h*1024
    float2 acc = make_float2(0.f, 0.f);
    int t = 0;                                        // t = (k*h) & 127
    #pragma unroll 8
    for (int h = 0; h < 128; ++h) {
        const float2 a  = src[(size_t)h * 1024];
        const float2 tw = twl[t];
        t = (t + k) & 127;
        acc.x += a.x * tw.x + a.y * tw.y;             // (ar+iai)(c-is)
        acc.y += a.y * tw.x - a.x * tw.y;
    }
    xft[(size_t)(b * 16 + k) * 1024 + n * 64 + c] = acc;
}

// Complex GEMM, full-K, fused Schmidt fold, direct transposed output:
//   grid 256 = (m 16, oq 16); block: out tile [64 rows][4 o], K = 1024 (n,c).
//   Bs[n,c,o] = sum_s (wr + i wi)[m,n,c,o,s] * 0.5  (32KB LDS, staged once)
//   thread = (row r = tid>>2, o-lane ol = tid&3): one complex accumulator.
//   Writes omT[b][m][o][k] (k innermost -- the layout k_idft consumes).
__global__ __launch_bounds__(256) void k_gemm2(const float2* __restrict__ xft,
                                               const float* __restrict__ wr,
                                               const float* __restrict__ wi,
                                               float2* __restrict__ omT) {
    __shared__ float2 Bs[4096];                       // [n16][c64][o4] 32KB
    const int oq = blockIdx.x & 15;
    const int m  = blockIdx.x >> 4;
    #pragma unroll
    for (int i = 0; i < 16; ++i) {                    // stage B, sum over s
        const int idx = threadIdx.x + 256 * i;        // 4096 = n*256 + c*4 + o
        const int nn = idx >> 8, cc = (idx >> 2) & 63, oo = idx & 3;
        const size_t wb = ((size_t)((m * 16 + nn) * 64 + cc) * 64 + oq * 4 + oo) * 4;
        const float4 r4 = *reinterpret_cast<const float4*>(wr + wb);
        const float4 i4 = *reinterpret_cast<const float4*>(wi + wb);
        Bs[idx] = make_float2((r4.x + r4.y + r4.z + r4.w) * 0.5f,
                              (i4.x + i4.y + i4.z + i4.w) * 0.5f);
    }
    __syncthreads();
    const int ol = threadIdx.x & 3;
    const int r  = threadIdx.x >> 2;                  // 0..63 = b*16+k
    const float4* xr = reinterpret_cast<const float4*>(xft + (size_t)r * 1024);
    float accx = 0.f, accy = 0.f;
    #pragma unroll 8
    for (int k2 = 0; k2 < 512; ++k2) {                // 2 complex per iter
        const float4 a  = xr[k2];                     // xft[r][2k2], [2k2+1]
        const float2 b0 = Bs[8 * k2 + ol];
        const float2 b1 = Bs[8 * k2 + 4 + ol];
        accx += a.x * b0.x - a.y * b0.y + a.z * b1.x - a.w * b1.y;
        accy += a.x * b0.y + a.y * b0.x + a.z * b1.y + a.w * b1.x;
    }
    const int b = r >> 4, k = r & 15;
    const int o = oq * 4 + ol;
    omT[(((size_t)b * 16 + m) * 64 + o) * 16 + k] = make_float2(accx, accy);
}

// Fused inverse: block = (b,h) = 512 blocks.
//   u_s[m][o] = sum_k omT[b][m][o][k] e^{+2pi i k h/128}   (cooperative, LDS)
//   out[b,h,w,o] = (1/16384) * sum_m Re(u_s[m][o] e^{+2pi i m w/128})
__global__ __launch_bounds__(256) void k_idft(const float2* __restrict__ omT,
                                              float* __restrict__ out) {
    __shared__ float2 u_s[1024];                      // [m16][o64] 8KB
    __shared__ float2 twl[128];
    init_trig_lds(twl);
    const int bid = blockIdx.x;                       // b*128 + h
    const int h = bid & 127, b = bid >> 7;
    __syncthreads();                                  // twl ready
    #pragma unroll
    for (int i = 0; i < 4; ++i) {                     // u-gen: 4 (m,o) per thread
        const int e = threadIdx.x + 256 * i;          // m*64 + o
        const float4* src = reinterpret_cast<const float4*>(
            omT + (((size_t)b * 16 + (e >> 6)) * 64 + (e & 63)) * 16);
        float re = 0.f, im = 0.f;
        int t = 0;                                    // (k*h) & 127, block-uniform
        #pragma unroll
        for (int k8 = 0; k8 < 8; ++k8) {
            const float4 q = src[k8];                 // k = 2k8, 2k8+1
            const float2 tw0 = twl[t]; t = (t + h) & 127;
            const float2 tw1 = twl[t]; t = (t + h) & 127;
            re += q.x * tw0.x - q.y * tw0.y + q.z * tw1.x - q.w * tw1.y;
            im += q.x * tw0.y + q.y * tw0.x + q.z * tw1.y + q.w * tw1.x;
        }
        u_s[e] = make_float2(re, im);
    }
    __syncthreads();
    const int o4 = threadIdx.x & 15;                  // 4 o's
    const int wg = threadIdx.x >> 4;                  // 8 w's
    const float inv = 1.0f / 16384.0f;
    #pragma unroll
    for (int i = 0; i < 8; ++i) {
        const int w = wg * 8 + i;
        float4 acc = make_float4(0.f, 0.f, 0.f, 0.f);
        int t = 0;                                    // (m*w) & 127
        #pragma unroll
        for (int mm = 0; mm < 16; ++mm) {
            const float2 tw  = twl[t];
            t = (t + w) & 127;
            const float4 u01 = *reinterpret_cast<const float4*>(&u_s[mm * 64 + o4 * 4]);
            const float4 u23 = *reinterpret_cast<const float4*>(&u_s[mm * 64 + o4 * 4 + 2]);
            acc.x += u01.x * tw.x - u01.y * tw.y;
            acc.y += u01.z * tw.x - u01.w * tw.y;
            acc.z += u23.x * tw.x - u23.y * tw.y;
            acc.w += u23.z * tw.x - u23.w * tw.y;
        }
        acc.x *= inv; acc.y *= inv; acc.z *= inv; acc.w *= inv;
        *reinterpret_cast<float4*>(out + ((size_t)bid * 128 + w) * 64 + o4 * 4) = acc;
    }
}

extern "C" void kernel_launch(void* const* d_in, const int* in_sizes, int n_in,
                              void* d_out, int out_size, void* d_ws, size_t ws_size,
                              hipStream_t stream) {
    const float* x  = (const float*)d_in[0];
    const float* wr = (const float*)d_in[1];
    const float* wi = (const float*)d_in[2];
    float* out = (float*)d_out;
    float* ws  = (float*)d_ws;

    float2* tmp1 = (float2*)(ws + TMP_OFF);
    float2* xft  = (float2*)(ws + XFT_OFF);
    float2* omT  = (float2*)(ws + OMT_OFF);

    k_dft_w<<<BATCH * 128, 256, 0, stream>>>(x, tmp1);
    k_dft_h<<<256, 256, 0, stream>>>(tmp1, xft);
    k_gemm2<<<256, 256, 0, stream>>>(xft, wr, wi, omT);
    k_idft <<<BATCH * 128, 256, 0, stream>>>(omT, out);
}

// Round 7
// 161.048 us; speedup vs baseline: 4.3340x; 1.0449x over previous
//
#include <hip/hip_runtime.h>

// QuantumSpectralConv: x[4,128,128,64] f32, W[16,16,64,64,4] re/im planes.
//   x_ft = DFT_{H,W}(x) truncated to 16x16 modes
//   om[b,k,m,o] = sum_{n,c} x_ft[b,k,n,c] * (sum_s W[m,n,c,o,s]) / 2
//   out = Re(iDFT zero-padded)  -> [4,128,128,64] f32
//
// 4-kernel pipeline. R6 lesson: the serial LDS twiddle chain (tw=twl[t];
// t=(t+d)&127) was latency-bound (~120cyc/LDS read on the critical path);
// all twiddles are now REGISTER rotations (tw *= e^{i theta}, theta const
// per thread, one sincosf at setup). k_idft phase-2 keeps u in registers
// (load LDS once, not 8x).

static constexpr int BATCH = 4;
static constexpr float STEP_C = 0.9987954562051724f;   // cos(2*pi/128)
static constexpr float STEP_S = 0.04906767432741801f;  // sin(2*pi/128)

// float offsets into workspace
static constexpr size_t TMP_OFF = 0;          // tmp1: 524288 complex (4.2MB)
static constexpr size_t XFT_OFF = 1048576;    // 65536 complex (0.5MB)
static constexpr size_t OMT_OFF = 1179648;    // 65536 complex (0.5MB)

__device__ __forceinline__ float2 cmulp(float2 a, float2 b) {  // a*b (+i)
    return make_float2(a.x * b.x - a.y * b.y, a.x * b.y + a.y * b.x);
}

// DFT over W: tmp1[b,h,n,c] = sum_w x[b,h,w,c] * e^{-2pi i n w/128}, n<16
// block per (b,h) = 512 blocks. Thread: one n (tid>>4), 4 c's (tid&15).
__global__ __launch_bounds__(256) void k_dft_w(const float* __restrict__ x,
                                               float2* __restrict__ tmp1) {
    __shared__ float4 xs[2048];                       // [128 w][16 c4] = 32KB
    const int bid = blockIdx.x;                       // b*128 + h
    const float4* x4 = reinterpret_cast<const float4*>(x) + (size_t)bid * 2048;
    #pragma unroll
    for (int i = 0; i < 8; ++i) xs[threadIdx.x + 256 * i] = x4[threadIdx.x + 256 * i];
    const int n  = threadIdx.x >> 4;
    const int c4 = threadIdx.x & 15;
    float rs, rc;                                     // rot = e^{+2pi i n/128}
    sincosf(6.283185307179586f * (float)n * 0.0078125f, &rs, &rc);
    const float2 rot = make_float2(rc, rs);
    __syncthreads();
    float4 ar = make_float4(0.f, 0.f, 0.f, 0.f);
    float4 ai = make_float4(0.f, 0.f, 0.f, 0.f);
    float2 tw = make_float2(1.f, 0.f);                // e^{+2pi i n w/128}
    #pragma unroll 8
    for (int w = 0; w < 128; ++w) {
        const float4 v = xs[w * 16 + c4];
        ar.x += v.x * tw.x; ai.x -= v.x * tw.y;
        ar.y += v.y * tw.x; ai.y -= v.y * tw.y;
        ar.z += v.z * tw.x; ai.z -= v.z * tw.y;
        ar.w += v.w * tw.x; ai.w -= v.w * tw.y;
        tw = cmulp(tw, rot);
    }
    float4* o = reinterpret_cast<float4*>(tmp1 + ((size_t)bid * 16 + n) * 64 + c4 * 4);
    o[0] = make_float4(ar.x, ai.x, ar.y, ai.y);
    o[1] = make_float4(ar.z, ai.z, ar.w, ai.w);
}

// DFT over H: xft[(b*16+k)*1024+n*64+c] = sum_h tmp1[b,h,n,c] e^{-2pi i k h/128}
// grid 512 = (b 4, k 16, nh 8); thread: (hs = tid>>7) h-half, ol = tid&127 ->
// (n1, c). Partial sums combined via tiny LDS reduce.
__global__ __launch_bounds__(256) void k_dft_h(const float2* __restrict__ tmp1,
                                               float2* __restrict__ xft) {
    __shared__ float2 red[128];
    const int bid = blockIdx.x;
    const int nh = bid & 7;
    const int k  = (bid >> 3) & 15;
    const int b  = bid >> 7;
    const int ol = threadIdx.x & 127;
    const int hs = threadIdx.x >> 7;
    const int c  = ol & 63;
    const int n  = nh * 2 + (ol >> 6);
    float rs, rc;                                     // rot = e^{+2pi i k/128}
    sincosf(6.283185307179586f * (float)k * 0.0078125f, &rs, &rc);
    const float2 rot = make_float2(rc, rs);
    // start angle: 2pi*k*(hs*64)/128 = pi*k*hs -> (+-1, 0)
    float2 tw = make_float2((hs && (k & 1)) ? -1.f : 1.f, 0.f);
    const float2* src = tmp1 + (size_t)b * 131072 + n * 64 + c + (size_t)hs * 65536;
    float2 acc = make_float2(0.f, 0.f);
    #pragma unroll 8
    for (int j = 0; j < 64; ++j) {
        const float2 a = src[(size_t)j * 1024];
        acc.x += a.x * tw.x + a.y * tw.y;             // conj twiddle: (c-is)
        acc.y += a.y * tw.x - a.x * tw.y;
        tw = cmulp(tw, rot);
    }
    if (hs) red[ol] = acc;
    __syncthreads();
    if (!hs) {
        const float2 r = red[ol];
        acc.x += r.x; acc.y += r.y;
        xft[(size_t)(b * 16 + k) * 1024 + n * 64 + c] = acc;
    }
}

// Complex GEMM, fused Schmidt fold, K-split x2 in-block:
//   grid 256 = (m 16, oq 16), 512 threads. Bs[n,c,o4] = sum_s W/2 (32KB).
//   thread (r = tid>>3, ol = (tid>>1)&3, ks = tid&1): half-K accumulator,
//   pair-reduced via shfl_xor(1). Writes omT[b][m][o][k] (k innermost).
__global__ __launch_bounds__(512) void k_gemm2(const float2* __restrict__ xft,
                                               const float* __restrict__ wr,
                                               const float* __restrict__ wi,
                                               float2* __restrict__ omT) {
    __shared__ float2 Bs[4096];                       // [n16][c64][o4] 32KB
    const int oq = blockIdx.x & 15;
    const int m  = blockIdx.x >> 4;
    #pragma unroll
    for (int i = 0; i < 8; ++i) {                     // stage B, sum over s
        const int idx = threadIdx.x + 512 * i;        // 4096 = n*256 + c*4 + o
        const int nn = idx >> 8, cc = (idx >> 2) & 63, oo = idx & 3;
        const size_t wb = ((size_t)((m * 16 + nn) * 64 + cc) * 64 + oq * 4 + oo) * 4;
        const float4 r4 = *reinterpret_cast<const float4*>(wr + wb);
        const float4 i4 = *reinterpret_cast<const float4*>(wi + wb);
        Bs[idx] = make_float2((r4.x + r4.y + r4.z + r4.w) * 0.5f,
                              (i4.x + i4.y + i4.z + i4.w) * 0.5f);
    }
    __syncthreads();
    const int r  = threadIdx.x >> 3;                  // 0..63 = b*16+k
    const int ol = (threadIdx.x >> 1) & 3;
    const int ks = threadIdx.x & 1;
    const float4* xr = reinterpret_cast<const float4*>(xft + (size_t)r * 1024) + ks * 256;
    float accx = 0.f, accy = 0.f;
    #pragma unroll 8
    for (int k2 = 0; k2 < 256; ++k2) {                // 2 complex per iter
        const float4 a  = xr[k2];
        const int base = 8 * (ks * 256 + k2);
        const float2 b0 = Bs[base + ol];
        const float2 b1 = Bs[base + 4 + ol];
        accx += a.x * b0.x - a.y * b0.y + a.z * b1.x - a.w * b1.y;
        accy += a.x * b0.y + a.y * b0.x + a.z * b1.y + a.w * b1.x;
    }
    accx += __shfl_xor(accx, 1);
    accy += __shfl_xor(accy, 1);
    if (ks == 0) {
        const int b = r >> 4, k = r & 15;
        const int o = oq * 4 + ol;
        omT[(((size_t)b * 16 + m) * 64 + o) * 16 + k] = make_float2(accx, accy);
    }
}

// Fused inverse: block = (b,h) = 512 blocks.
//   u_s[m][o] = sum_k omT[b][m][o][k] e^{+2pi i k h/128}   (phase 1, LDS)
//   out[b,h,w,o] = (1/16384) * sum_m Re(u_s[m][o] e^{+2pi i m w/128})
// All twiddles register-rotated; u loaded to registers ONCE for phase 2.
__global__ __launch_bounds__(256) void k_idft(const float2* __restrict__ omT,
                                              float* __restrict__ out) {
    __shared__ float2 u_s[1024];                      // [m16][o64] 8KB
    const int bid = blockIdx.x;                       // b*128 + h
    const int h = bid & 127, b = bid >> 7;
    float hs_, hc_;                                   // rot_k = e^{+2pi i h/128}
    sincosf(6.283185307179586f * (float)h * 0.0078125f, &hs_, &hc_);
    const float2 rotk = make_float2(hc_, hs_);
    #pragma unroll
    for (int i = 0; i < 4; ++i) {                     // phase 1: 4 u per thread
        const int e = threadIdx.x + 256 * i;          // m*64 + o
        const float4* src = reinterpret_cast<const float4*>(
            omT + (((size_t)b * 16 + (e >> 6)) * 64 + (e & 63)) * 16);
        float re = 0.f, im = 0.f;
        float2 tw = make_float2(1.f, 0.f);            // e^{+2pi i k h/128}
        #pragma unroll
        for (int k8 = 0; k8 < 8; ++k8) {
            const float4 q = src[k8];                 // k = 2k8, 2k8+1
            re += q.x * tw.x - q.y * tw.y; im += q.x * tw.y + q.y * tw.x;
            tw = cmulp(tw, rotk);
            re += q.z * tw.x - q.w * tw.y; im += q.z * tw.y + q.w * tw.x;
            tw = cmulp(tw, rotk);
        }
        u_s[e] = make_float2(re, im);
    }
    __syncthreads();
    const int o4 = threadIdx.x & 15;                  // 4 o's
    const int wg = threadIdx.x >> 4;                  // 8 w's
    float4 va[16], vb[16];                            // u strip in registers
    #pragma unroll
    for (int mm = 0; mm < 16; ++mm) {
        const float4* up = reinterpret_cast<const float4*>(&u_s[mm * 64 + o4 * 4]);
        va[mm] = up[0];                               // complex o4*4+0, +1
        vb[mm] = up[1];                               // complex o4*4+2, +3
    }
    float ws_, wc_;                                   // rot_m = e^{+2pi i w/128}
    sincosf(6.283185307179586f * (float)(wg * 8) * 0.0078125f, &ws_, &wc_);
    float2 rotm = make_float2(wc_, ws_);
    const float2 step = make_float2(STEP_C, STEP_S);  // advance w by 1
    const float inv = 1.0f / 16384.0f;
    #pragma unroll
    for (int i = 0; i < 8; ++i) {
        const int w = wg * 8 + i;
        float4 acc = make_float4(0.f, 0.f, 0.f, 0.f);
        float2 tw = make_float2(1.f, 0.f);            // e^{+2pi i m w/128}
        #pragma unroll
        for (int mm = 0; mm < 16; ++mm) {
            acc.x += va[mm].x * tw.x - va[mm].y * tw.y;
            acc.y += va[mm].z * tw.x - va[mm].w * tw.y;
            acc.z += vb[mm].x * tw.x - vb[mm].y * tw.y;
            acc.w += vb[mm].z * tw.x - vb[mm].w * tw.y;
            tw = cmulp(tw, rotm);
        }
        acc.x *= inv; acc.y *= inv; acc.z *= inv; acc.w *= inv;
        *reinterpret_cast<float4*>(out + ((size_t)bid * 128 + w) * 64 + o4 * 4) = acc;
        rotm = cmulp(rotm, step);
    }
}

extern "C" void kernel_launch(void* const* d_in, const int* in_sizes, int n_in,
                              void* d_out, int out_size, void* d_ws, size_t ws_size,
                              hipStream_t stream) {
    const float* x  = (const float*)d_in[0];
    const float* wr = (const float*)d_in[1];
    const float* wi = (const float*)d_in[2];
    float* out = (float*)d_out;
    float* ws  = (float*)d_ws;

    float2* tmp1 = (float2*)(ws + TMP_OFF);
    float2* xft  = (float2*)(ws + XFT_OFF);
    float2* omT  = (float2*)(ws + OMT_OFF);

    k_dft_w<<<BATCH * 128, 256, 0, stream>>>(x, tmp1);
    k_dft_h<<<512, 256, 0, stream>>>(tmp1, xft);
    k_gemm2<<<256, 512, 0, stream>>>(xft, wr, wi, omT);
    k_idft <<<BATCH * 128, 256, 0, stream>>>(omT, out);
}